// Round 7
// baseline (281.541 us; speedup 1.0000x reference)
//
#include <hip/hip_runtime.h>

#define CIN    96
#define COUT   192
#define EPSBN  1e-5f
#define GRID   588           // 196 pixel-tiles (256 px) x 3 co-blocks

// ---------------- ws layout (bytes), total < 61,702,144 (proven fit) ----------------
#define W1B_OFF  0u          // bf16 [192][9][96]   -> 331776 B
#define W2B_OFF  331776u     // bf16 [192][9][192]  -> 663552 B
#define WSB_OFF  995328u     // bf16 [192][96]      -> 36864 B
#define CS_OFF   1032192u    // scales/biases f32
#define XT_OFF   1048576u    // bf16 [64][56][56][96] -> 38535168 B (unpadded NHWC)
#define ACT_OFF  39583744u   // bf16 [64][30][30][192] -> 22118400 B (padded NHWC)

typedef __attribute__((ext_vector_type(8))) short bf16x8;
typedef __attribute__((ext_vector_type(4))) short bf16x4;
typedef __attribute__((ext_vector_type(4))) float f32x4;

__device__ __forceinline__ short f2bf(float f) {
    unsigned u = __float_as_uint(f);
    u += 0x7fffu + ((u >> 16) & 1u);
    return (short)(u >> 16);
}

// bijective XCD chunk swizzle for 588 blocks (q=73, r=4): consecutive lbids
// (the 3 co-blocks of one pixel tile + neighbors) land on one XCD.
__device__ __forceinline__ int swz_bid(int bid) {
    int xcd = bid & 7, lin = bid >> 3;
    int base = (xcd < 4) ? xcd * 74 : 296 + (xcd - 4) * 73;
    return base + lin;
}

__device__ __forceinline__ float rational_eval(float v, const float* nm, const float* dn) {
    float p = nm[5];
    p = p * v + nm[4];
    p = p * v + nm[3];
    p = p * v + nm[2];
    p = p * v + nm[1];
    p = p * v + nm[0];
    float xa = fabsf(v);
    float q = 1.0f;
    float pw = xa;
    q += dn[0] * pw; pw *= xa;
    q += dn[1] * pw; pw *= xa;
    q += dn[2] * pw; pw *= xa;
    q += dn[3] * pw;
    float inv = __builtin_amdgcn_rcpf(q);
    inv = inv * (2.0f - q * inv);
    return p * inv;
}

__device__ __forceinline__ void sel_coeffs(int v, const float cnm[3][6], const float cdn[3][4],
                                           float nm[6], float dn[4]) {
#pragma unroll
    for (int i = 0; i < 6; i++) nm[i] = (v == 0) ? cnm[0][i] : ((v == 1) ? cnm[1][i] : cnm[2][i]);
#pragma unroll
    for (int i = 0; i < 4; i++) dn[i] = (v == 0) ? cdn[0][i] : ((v == 1) ? cdn[1][i] : cdn[2][i]);
}

#define DOMFMA(Af, Bf)                                                                   \
    do {                                                                                 \
        _Pragma("unroll") for (int m_ = 0; m_ < 4; ++m_)                                 \
            _Pragma("unroll") for (int n_ = 0; n_ < 4; ++n_)                             \
                acc[m_][n_] = __builtin_amdgcn_mfma_f32_16x16x32_bf16(Af[m_], Bf[n_],    \
                                                                      acc[m_][n_], 0, 0, 0); \
    } while (0)

// ---------------- prep kernels ----------------
extern "C" __global__ void prep_scales_kernel(
    const float* g1, const float* b1, const float* m1, const float* v1,
    const float* g2, const float* b2, const float* m2, const float* v2,
    const float* gs, const float* bs, const float* ms, const float* vs,
    float* cs)
{
    int i = threadIdx.x;
    if (i < COUT) {
        float a1 = g1[i] * rsqrtf(v1[i] + EPSBN);
        float a2 = g2[i] * rsqrtf(v2[i] + EPSBN);
        float a3 = gs[i] * rsqrtf(vs[i] + EPSBN);
        cs[i]       = a1;
        cs[192 + i] = a2;
        cs[384 + i] = a3;
        cs[576 + i] = b1[i] - m1[i] * a1;                          // bias1
        cs[768 + i] = (b2[i] - m2[i] * a2) + (bs[i] - ms[i] * a3); // bias2 + biass
    }
}

// w [co][ci][kpos] (OIHW) -> wb [co][kpos][ci], scaled by s[co]
extern "C" __global__ void prep_w_kernel(const float* __restrict__ w, const float* __restrict__ s,
                                         short* __restrict__ wb, int CI, int KP, int total)
{
    int i = blockIdx.x * 256 + threadIdx.x;
    if (i >= total) return;
    int co = i / (CI * KP);
    int r  = i - co * CI * KP;
    int kpos = r / CI;
    int ci = r - kpos * CI;
    wb[i] = f2bf(w[(co * CI + ci) * KP + kpos] * s[co]);
}

// zero the border ring of a [64][H][H][C] bf16 buffer
extern "C" __global__ void ring_zero_kernel(short* __restrict__ buf, int H, int C, int total)
{
    int ring = 2 * H + 2 * (H - 2);
    int i = blockIdx.x * 256 + threadIdx.x;
    if (i >= total) return;
    int c = i % C;
    int t = i / C;
    int rp = t % ring;
    int n = t / ring;
    int h, w;
    if (rp < H)           { h = 0;          w = rp; }
    else if (rp < 2 * H)  { h = H - 1;      w = rp - H; }
    else { int k = rp - 2 * H; h = (k >> 1) + 1; w = (k & 1) ? (H - 1) : 0; }
    buf[((n * H + h) * H + w) * C + c] = 0;
}

// x NCHW f32 [64][96][56][56] -> xt NHWC bf16 [64][56][56][96] (vectorized)
extern "C" __global__ __launch_bounds__(256)
void xpose_kernel(const float* __restrict__ x, short* __restrict__ xt)
{
    __shared__ float t[96 * 57];
    int b = blockIdx.x;
    int n = b / 56, h = b - n * 56;
    const float* src = x + n * (96 * 3136) + h * 56;
    for (int i = threadIdx.x; i < 96 * 28; i += 256) {
        int c = i / 28, w2 = i - c * 28;
        float2 v = *(const float2*)&src[c * 3136 + w2 * 2];
        t[c * 57 + w2 * 2]     = v.x;
        t[c * 57 + w2 * 2 + 1] = v.y;
    }
    __syncthreads();
    unsigned* dst = (unsigned*)(xt + (n * 56 + h) * 56 * 96);
    for (int i = threadIdx.x; i < 56 * 48; i += 256) {
        int w = i / 48, cp = i - w * 48;
        unsigned lo = (unsigned short)f2bf(t[(2 * cp) * 57 + w]);
        unsigned hi = (unsigned short)f2bf(t[(2 * cp + 1) * 57 + w]);
        dst[w * 48 + cp] = lo | (hi << 16);
    }
}

// ---------------- kernel A: conv1(3x3 s2)+BN1+rational -> act (NHWC bf16, padded) ----------------
// Pure register GEMM: no LDS, no barriers. Fragments load straight global->VGPR.
extern "C" __global__ __launch_bounds__(256, 3)
void convA_kernel(const short* __restrict__ xt,
                  const short* __restrict__ w1b,
                  const float* __restrict__ bias1,
                  const float* __restrict__ num_r, const float* __restrict__ den_r,
                  const float* __restrict__ num_g, const float* __restrict__ den_g,
                  const float* __restrict__ num_b, const float* __restrict__ den_b,
                  short* __restrict__ act)
{
    const int tid  = threadIdx.x;
    const int lane = tid & 63;
    const int wave = tid >> 6;
    const int lbid = swz_bid(blockIdx.x);
    const int co0  = (lbid % 3) * 64;
    const int p0   = (lbid / 3) * 256;

    const int l15 = lane & 15;
    const int kl8 = (lane >> 4) * 8;     // element offset in K per fragment layout

    // per-lane B (pixel) bases and border predicates
    int xtoff[4];
    int topn[4], leftn[4];
#pragma unroll
    for (int n = 0; n < 4; ++n) {
        int p = p0 + wave * 64 + n * 16 + l15;
        int img = p / 784; int pr = p - img * 784;
        int oh = pr / 28;  int ow = pr - oh * 28;
        xtoff[n] = ((img * 56 + 2 * oh) * 56 + 2 * ow) * 96 + kl8;
        topn[n]  = (oh == 0);
        leftn[n] = (ow == 0);
    }
    // per-lane A (weight-row) bases
    int aoff[4];
#pragma unroll
    for (int m = 0; m < 4; ++m) aoff[m] = (co0 + m * 16 + l15) * 864 + kl8;

#define LOADT_A(Af, Bf, t_)                                                              \
    do {                                                                                 \
        int t__ = (t_);                                                                  \
        int kpos__ = t__ / 3, cb__ = t__ - 3 * kpos__;                                   \
        int kh__ = kpos__ / 3, kw__ = kpos__ - 3 * kh__;                                 \
        int ka__ = t__ * 32;                                                             \
        int kb__ = ((kh__ - 1) * 56 + (kw__ - 1)) * 96 + cb__ * 32;                      \
        _Pragma("unroll") for (int m_ = 0; m_ < 4; ++m_)                                 \
            Af[m_] = *(const bf16x8*)&w1b[aoff[m_] + ka__];                              \
        _Pragma("unroll") for (int n_ = 0; n_ < 4; ++n_) {                               \
            bf16x8 v__ = *(const bf16x8*)&xt[xtoff[n_] + kb__];                          \
            bool ok__ = !((kh__ == 0) && topn[n_]) && !((kw__ == 0) && leftn[n_]);       \
            Bf[n_] = ok__ ? v__ : (bf16x8)(short)0;                                      \
        }                                                                                \
    } while (0)

    f32x4 acc[4][4];
#pragma unroll
    for (int m = 0; m < 4; m++)
#pragma unroll
        for (int n = 0; n < 4; n++) acc[m][n] = (f32x4){0.f, 0.f, 0.f, 0.f};

    bf16x8 A0[4], B0[4], A1[4], B1[4];
    LOADT_A(A0, B0, 0);
    for (int t = 0; t + 2 <= 27; t += 2) {      // K = 864 = 27 steps of 32
        LOADT_A(A1, B1, t + 1);
        DOMFMA(A0, B0);
        if (t + 2 < 27) LOADT_A(A0, B0, t + 2);
        DOMFMA(A1, B1);
    }
    DOMFMA(A0, B0);                              // t = 26

    // epilogue: bias + rational -> act (NHWC, packed short4)
    float cnm[3][6], cdn[3][4];
#pragma unroll
    for (int i = 0; i < 6; i++) { cnm[0][i] = num_r[i]; cnm[1][i] = num_g[i]; cnm[2][i] = num_b[i]; }
#pragma unroll
    for (int i = 0; i < 4; i++) { cdn[0][i] = fabsf(den_r[i]); cdn[1][i] = fabsf(den_g[i]); cdn[2][i] = fabsf(den_b[i]); }

    int abase[4];
#pragma unroll
    for (int n = 0; n < 4; ++n) {
        int pp = p0 + wave * 64 + n * 16 + l15;
        int n2 = pp / 784; int r2 = pp - n2 * 784;
        int oh2 = r2 / 28; int ow2 = r2 - oh2 * 28;
        abase[n] = ((n2 * 30 + oh2 + 1) * 30 + ow2 + 1) * 192;
    }
#pragma unroll
    for (int m = 0; m < 4; ++m) {
        int cob = co0 + m * 16 + ((lane >> 4) << 2);
        float res[4][4];
#pragma unroll
        for (int r = 0; r < 4; ++r) {
            float nm[6], dn[4];
            sel_coeffs((cob + r) % 3, cnm, cdn, nm, dn);
            float bv = bias1[cob + r];
#pragma unroll
            for (int n = 0; n < 4; ++n)
                res[n][r] = rational_eval(acc[m][n][r] + bv, nm, dn);
        }
#pragma unroll
        for (int n = 0; n < 4; ++n) {
            bf16x4 pk;
#pragma unroll
            for (int r = 0; r < 4; ++r) pk[r] = f2bf(res[n][r]);
            *(bf16x4*)&act[abase[n] + cob] = pk;
        }
    }
#undef LOADT_A
}

// ---------------- kernel B: shortcut(1x1 s2, K=96) + conv2(3x3 s1, K=1728) into one acc;
//                  + fused bias + rational -> out (NCHW f32). Pure register GEMM. ----------------
extern "C" __global__ __launch_bounds__(256, 3)
void convB_kernel(const short* __restrict__ act,
                  const short* __restrict__ xt,
                  const short* __restrict__ w2b,
                  const short* __restrict__ wsb,
                  const float* __restrict__ bias2s,
                  const float* __restrict__ num_r, const float* __restrict__ den_r,
                  const float* __restrict__ num_g, const float* __restrict__ den_g,
                  const float* __restrict__ num_b, const float* __restrict__ den_b,
                  float* __restrict__ outp)
{
    const int tid  = threadIdx.x;
    const int lane = tid & 63;
    const int wave = tid >> 6;
    const int lbid = swz_bid(blockIdx.x);
    const int co0  = (lbid % 3) * 64;
    const int p0   = (lbid / 3) * 256;

    const int l15 = lane & 15;
    const int kl8 = (lane >> 4) * 8;

    int actoff[4], xtoff[4];
#pragma unroll
    for (int n = 0; n < 4; ++n) {
        int p = p0 + wave * 64 + n * 16 + l15;
        int img = p / 784; int pr = p - img * 784;
        int oh = pr / 28;  int ow = pr - oh * 28;
        actoff[n] = ((img * 30 + oh) * 30 + ow) * 192 + kl8;           // padded act base
        xtoff[n]  = ((img * 56 + 2 * oh) * 56 + 2 * ow) * 96 + kl8;    // center tap
    }
    int aoffW[4], aoffS[4];
#pragma unroll
    for (int m = 0; m < 4; ++m) {
        int row = co0 + m * 16 + l15;
        aoffW[m] = row * 1728 + kl8;
        aoffS[m] = row * 96 + kl8;
    }

#define LOADT_B(Af, Bf, t_)                                                              \
    do {                                                                                 \
        int t__ = (t_);                                                                  \
        if (t__ < 3) {                                                                   \
            int k0__ = t__ * 32;                                                         \
            _Pragma("unroll") for (int m_ = 0; m_ < 4; ++m_)                             \
                Af[m_] = *(const bf16x8*)&wsb[aoffS[m_] + k0__];                         \
            _Pragma("unroll") for (int n_ = 0; n_ < 4; ++n_)                             \
                Bf[n_] = *(const bf16x8*)&xt[xtoff[n_] + k0__];                          \
        } else {                                                                         \
            int u__ = t__ - 3;                                                           \
            int kpos__ = u__ / 6, cb__ = u__ - 6 * kpos__;                               \
            int kh__ = kpos__ / 3, kw__ = kpos__ - 3 * kh__;                             \
            int ka__ = u__ * 32;                                                         \
            int kb__ = (kh__ * 30 + kw__) * 192 + cb__ * 32;                             \
            _Pragma("unroll") for (int m_ = 0; m_ < 4; ++m_)                             \
                Af[m_] = *(const bf16x8*)&w2b[aoffW[m_] + ka__];                         \
            _Pragma("unroll") for (int n_ = 0; n_ < 4; ++n_)                             \
                Bf[n_] = *(const bf16x8*)&act[actoff[n_] + kb__];                        \
        }                                                                                \
    } while (0)

    f32x4 acc[4][4];
#pragma unroll
    for (int m = 0; m < 4; m++)
#pragma unroll
        for (int n = 0; n < 4; n++) acc[m][n] = (f32x4){0.f, 0.f, 0.f, 0.f};

    bf16x8 A0[4], B0[4], A1[4], B1[4];
    LOADT_B(A0, B0, 0);
    for (int t = 0; t + 2 <= 57; t += 2) {      // 3 shortcut + 54 conv2 steps
        LOADT_B(A1, B1, t + 1);
        DOMFMA(A0, B0);
        if (t + 2 < 57) LOADT_B(A0, B0, t + 2);
        DOMFMA(A1, B1);
    }
    DOMFMA(A0, B0);                              // t = 56

    float cnm[3][6], cdn[3][4];
#pragma unroll
    for (int i = 0; i < 6; i++) { cnm[0][i] = num_r[i]; cnm[1][i] = num_g[i]; cnm[2][i] = num_b[i]; }
#pragma unroll
    for (int i = 0; i < 4; i++) { cdn[0][i] = fabsf(den_r[i]); cdn[1][i] = fabsf(den_g[i]); cdn[2][i] = fabsf(den_b[i]); }

    int obase[4];
#pragma unroll
    for (int n = 0; n < 4; ++n) {
        int pp = p0 + wave * 64 + n * 16 + l15;
        int n2 = pp / 784; int r2 = pp - n2 * 784;
        int oh2 = r2 / 28; int ow2 = r2 - oh2 * 28;
        obase[n] = n2 * (COUT * 784) + oh2 * 28 + ow2;
    }
#pragma unroll
    for (int m = 0; m < 4; ++m) {
        int cob = co0 + m * 16 + ((lane >> 4) << 2);
#pragma unroll
        for (int r = 0; r < 4; ++r) {
            float nm[6], dn[4];
            sel_coeffs((cob + r) % 3, cnm, cdn, nm, dn);
            float bv = bias2s[cob + r];
#pragma unroll
            for (int n = 0; n < 4; ++n) {
                int idx = obase[n] + (cob + r) * 784;
                outp[idx] = rational_eval(acc[m][n][r] + bv, nm, dn);
            }
        }
    }
#undef LOADT_B
}

// ---------------- launcher ----------------
extern "C" void kernel_launch(void* const* d_in, const int* in_sizes, int n_in,
                              void* d_out, int out_size, void* d_ws, size_t ws_size,
                              hipStream_t stream)
{
    const float* x      = (const float*)d_in[0];
    const float* w1     = (const float*)d_in[1];
    const float* gamma1 = (const float*)d_in[2];
    const float* beta1  = (const float*)d_in[3];
    const float* mean1  = (const float*)d_in[4];
    const float* var1   = (const float*)d_in[5];
    const float* num_r  = (const float*)d_in[6];
    const float* den_r  = (const float*)d_in[7];
    const float* num_g  = (const float*)d_in[8];
    const float* den_g  = (const float*)d_in[9];
    const float* num_b  = (const float*)d_in[10];
    const float* den_b  = (const float*)d_in[11];
    const float* w2     = (const float*)d_in[12];
    const float* gamma2 = (const float*)d_in[13];
    const float* beta2  = (const float*)d_in[14];
    const float* mean2  = (const float*)d_in[15];
    const float* var2   = (const float*)d_in[16];
    const float* wsc    = (const float*)d_in[17];
    const float* gammas = (const float*)d_in[18];
    const float* betas  = (const float*)d_in[19];
    const float* means  = (const float*)d_in[20];
    const float* vars_  = (const float*)d_in[21];

    char* base = (char*)d_ws;
    short* w1b  = (short*)(base + W1B_OFF);
    short* w2b  = (short*)(base + W2B_OFF);
    short* wsb  = (short*)(base + WSB_OFF);
    float* cs   = (float*)(base + CS_OFF);
    short* xt   = (short*)(base + XT_OFF);
    short* act  = (short*)(base + ACT_OFF);
    float* outp = (float*)d_out;

    float* bias1  = cs + 576;
    float* bias2s = cs + 768;

    prep_scales_kernel<<<1, 256, 0, stream>>>(gamma1, beta1, mean1, var1,
                                              gamma2, beta2, mean2, var2,
                                              gammas, betas, means, vars_, cs);

    prep_w_kernel<<<(COUT * CIN * 9 + 255) / 256, 256, 0, stream>>>(w1, cs, w1b, CIN, 9, COUT * CIN * 9);
    prep_w_kernel<<<(COUT * COUT * 9 + 255) / 256, 256, 0, stream>>>(w2, cs + 192, w2b, COUT, 9, COUT * COUT * 9);
    prep_w_kernel<<<(COUT * CIN + 255) / 256, 256, 0, stream>>>(wsc, cs + 384, wsb, CIN, 1, COUT * CIN);

    {
        int tot_a = 64 * (2 * 30 + 2 * 28) * 192;
        ring_zero_kernel<<<(tot_a + 255) / 256, 256, 0, stream>>>(act, 30, 192, tot_a);
    }

    xpose_kernel<<<64 * 56, 256, 0, stream>>>(x, xt);

    convA_kernel<<<GRID, 256, 0, stream>>>(xt, w1b, bias1,
                                           num_r, den_r, num_g, den_g, num_b, den_b,
                                           act);

    convB_kernel<<<GRID, 256, 0, stream>>>(act, xt, w2b, wsb, bias2s,
                                           num_r, den_r, num_g, den_g, num_b, den_b,
                                           outp);
}

// Round 8
// 208.955 us; speedup vs baseline: 1.3474x; 1.3474x over previous
//
#include <hip/hip_runtime.h>

#define CIN    96
#define COUT   192
#define EPSBN  1e-5f
#define GRID   588           // 196 pixel-tiles (256 px) x 3 co-blocks

// ---------------- ws layout (bytes), total < 61,702,144 (proven fit) ----------------
#define W1B_OFF  0u          // bf16 [192][9][96]   -> 331776 B
#define W2B_OFF  331776u     // bf16 [192][9][192]  -> 663552 B
#define WSB_OFF  995328u     // bf16 [192][96]      -> 36864 B
#define CS_OFF   1032192u    // scales/biases f32
#define ZB_OFF   1040384u    // 128 B zero scratch
#define XT_OFF   1048576u    // bf16 [64][56][56][96] -> 38535168 B (unpadded NHWC)
#define ACT_OFF  39583744u   // bf16 [64][30][30][192] -> 22118400 B (padded NHWC)

typedef __attribute__((ext_vector_type(8))) short bf16x8;
typedef __attribute__((ext_vector_type(4))) short bf16x4;
typedef __attribute__((ext_vector_type(4))) float f32x4;

__device__ __forceinline__ short f2bf(float f) {
    unsigned u = __float_as_uint(f);
    u += 0x7fffu + ((u >> 16) & 1u);
    return (short)(u >> 16);
}

// swizzled LDS read index (shorts): [rows][32 k], 16B-slot XOR on (row>>1)&3
__device__ __forceinline__ int lidx(int row, int slot) {
    return row * 32 + ((slot ^ ((row >> 1) & 3)) << 3);
}

// direct global->LDS, 16B per lane; LDS dest = wave-uniform base + lane*16
__device__ __forceinline__ void gload16(const short* g, short* l) {
    __builtin_amdgcn_global_load_lds(
        (const __attribute__((address_space(1))) void*)g,
        (__attribute__((address_space(3))) void*)l, 16, 0, 0);
}

// bijective XCD chunk swizzle for 588 blocks (q=73, r=4): consecutive lbids
// (the 3 co-blocks of one pixel tile + neighbors) land on one XCD.
__device__ __forceinline__ int swz_bid(int bid) {
    int xcd = bid & 7, lin = bid >> 3;
    int base = (xcd < 4) ? xcd * 74 : 296 + (xcd - 4) * 73;
    return base + lin;
}

__device__ __forceinline__ int nxt3(int b) { return b == 2 ? 0 : b + 1; }

__device__ __forceinline__ float rational_eval(float v, const float* nm, const float* dn) {
    float p = nm[5];
    p = p * v + nm[4];
    p = p * v + nm[3];
    p = p * v + nm[2];
    p = p * v + nm[1];
    p = p * v + nm[0];
    float xa = fabsf(v);
    float q = 1.0f;
    float pw = xa;
    q += dn[0] * pw; pw *= xa;
    q += dn[1] * pw; pw *= xa;
    q += dn[2] * pw; pw *= xa;
    q += dn[3] * pw;
    float inv = __builtin_amdgcn_rcpf(q);
    inv = inv * (2.0f - q * inv);
    return p * inv;
}

__device__ __forceinline__ void sel_coeffs(int v, const float cnm[3][6], const float cdn[3][4],
                                           float nm[6], float dn[4]) {
#pragma unroll
    for (int i = 0; i < 6; i++) nm[i] = (v == 0) ? cnm[0][i] : ((v == 1) ? cnm[1][i] : cnm[2][i]);
#pragma unroll
    for (int i = 0; i < 4; i++) dn[i] = (v == 0) ? cdn[0][i] : ((v == 1) ? cdn[1][i] : cdn[2][i]);
}

// 4x4 fragment compute on rotating buffer `buf`
#define COMPUTE(A, buf)                                                                        \
    do {                                                                                       \
        bf16x8 af[4], bfv[4];                                                                  \
        _Pragma("unroll") for (int m_ = 0; m_ < 4; ++m_) af[m_] =                              \
            *(const bf16x8*)&lA[(buf) * 2048 + ard[m_]];                                       \
        _Pragma("unroll") for (int n_ = 0; n_ < 4; ++n_) bfv[n_] =                             \
            *(const bf16x8*)&lB[(buf) * 8192 + brd[n_]];                                       \
        _Pragma("unroll") for (int m_ = 0; m_ < 4; ++m_)                                       \
            _Pragma("unroll") for (int n_ = 0; n_ < 4; ++n_)                                   \
                A[m_][n_] = __builtin_amdgcn_mfma_f32_16x16x32_bf16(af[m_], bfv[n_],           \
                                                                    A[m_][n_], 0, 0, 0);      \
    } while (0)

#define WAITV(N) asm volatile("s_waitcnt vmcnt(" #N ")" ::: "memory")

// ---------------- prep kernels ----------------
extern "C" __global__ void prep_scales_kernel(
    const float* g1, const float* b1, const float* m1, const float* v1,
    const float* g2, const float* b2, const float* m2, const float* v2,
    const float* gs, const float* bs, const float* ms, const float* vs,
    float* cs, float* zb)
{
    int i = threadIdx.x;
    if (i < 32) zb[i] = 0.f;
    if (i < COUT) {
        float a1 = g1[i] * rsqrtf(v1[i] + EPSBN);
        float a2 = g2[i] * rsqrtf(v2[i] + EPSBN);
        float a3 = gs[i] * rsqrtf(vs[i] + EPSBN);
        cs[i]       = a1;
        cs[192 + i] = a2;
        cs[384 + i] = a3;
        cs[576 + i] = b1[i] - m1[i] * a1;                          // bias1
        cs[768 + i] = (b2[i] - m2[i] * a2) + (bs[i] - ms[i] * a3); // bias2 + biass
    }
}

// w [co][ci][kpos] (OIHW) -> wb [co][kpos][ci], scaled by s[co]
extern "C" __global__ void prep_w_kernel(const float* __restrict__ w, const float* __restrict__ s,
                                         short* __restrict__ wb, int CI, int KP, int total)
{
    int i = blockIdx.x * 256 + threadIdx.x;
    if (i >= total) return;
    int co = i / (CI * KP);
    int r  = i - co * CI * KP;
    int kpos = r / CI;
    int ci = r - kpos * CI;
    wb[i] = f2bf(w[(co * CI + ci) * KP + kpos] * s[co]);
}

// zero the border ring of a [64][H][H][C] bf16 buffer
extern "C" __global__ void ring_zero_kernel(short* __restrict__ buf, int H, int C, int total)
{
    int ring = 2 * H + 2 * (H - 2);
    int i = blockIdx.x * 256 + threadIdx.x;
    if (i >= total) return;
    int c = i % C;
    int t = i / C;
    int rp = t % ring;
    int n = t / ring;
    int h, w;
    if (rp < H)           { h = 0;          w = rp; }
    else if (rp < 2 * H)  { h = H - 1;      w = rp - H; }
    else { int k = rp - 2 * H; h = (k >> 1) + 1; w = (k & 1) ? (H - 1) : 0; }
    buf[((n * H + h) * H + w) * C + c] = 0;
}

// x NCHW f32 [64][96][56][56] -> xt NHWC bf16 [64][56][56][96] (vectorized)
extern "C" __global__ __launch_bounds__(256)
void xpose_kernel(const float* __restrict__ x, short* __restrict__ xt)
{
    __shared__ float t[96 * 57];
    int b = blockIdx.x;
    int n = b / 56, h = b - n * 56;
    const float* src = x + n * (96 * 3136) + h * 56;
    for (int i = threadIdx.x; i < 96 * 28; i += 256) {
        int c = i / 28, w2 = i - c * 28;
        float2 v = *(const float2*)&src[c * 3136 + w2 * 2];
        t[c * 57 + w2 * 2]     = v.x;
        t[c * 57 + w2 * 2 + 1] = v.y;
    }
    __syncthreads();
    unsigned* dst = (unsigned*)(xt + (n * 56 + h) * 56 * 96);
    for (int i = threadIdx.x; i < 56 * 48; i += 256) {
        int w = i / 48, cp = i - w * 48;
        unsigned lo = (unsigned short)f2bf(t[(2 * cp) * 57 + w]);
        unsigned hi = (unsigned short)f2bf(t[(2 * cp + 1) * 57 + w]);
        dst[w * 48 + cp] = lo | (hi << 16);
    }
}

// ---------------- kernel A: conv1(3x3 s2)+BN1+rational -> act (NHWC bf16, padded) ----------------
extern "C" __global__ __launch_bounds__(256)
void convA_kernel(const short* __restrict__ xt,
                  const short* __restrict__ w1b,
                  const short* __restrict__ zbuf,
                  const float* __restrict__ bias1,
                  const float* __restrict__ num_r, const float* __restrict__ den_r,
                  const float* __restrict__ num_g, const float* __restrict__ den_g,
                  const float* __restrict__ num_b, const float* __restrict__ den_b,
                  short* __restrict__ act)
{
    __shared__ short lA[3 * 2048];   // 64co x 32k per buffer
    __shared__ short lB[3 * 8192];   // 256px x 32k per buffer

    const int tid  = threadIdx.x;
    const int lane = tid & 63;
    const int wave = tid >> 6;
    const int lbid = swz_bid(blockIdx.x);
    const int co0  = (lbid % 3) * 64;
    const int p0   = (lbid / 3) * 256;

    // staging: thread -> (row = tid>>2, linear 16B slot = tid&3); source slot swizzled
    const int swz8 = ((tid & 3) ^ ((tid >> 3) & 3)) * 8;
    const int arow = tid >> 2;
    int xb0[4];
    bool top[4], left[4];
#pragma unroll
    for (int i = 0; i < 4; ++i) {
        int p = p0 + arow + i * 64;
        int n = p / 784; int pr = p - n * 784;
        int oh = pr / 28; int ow = pr - oh * 28;
        xb0[i] = ((n * 56 + 2 * oh) * 56 + 2 * ow) * 96 + swz8;
        top[i]  = (oh == 0);
        left[i] = (ow == 0);
    }
    const int aw1 = (co0 + arow) * 864 + swz8;

    const int ksl = lane >> 4;
    int ard[4], brd[4];
#pragma unroll
    for (int m = 0; m < 4; ++m) ard[m] = lidx(m * 16 + (lane & 15), ksl);
#pragma unroll
    for (int n = 0; n < 4; ++n) brd[n] = lidx(wave * 64 + n * 16 + (lane & 15), ksl);

    auto stage = [&](int buf, int t) {
        int kpos = t / 3, cb = t - 3 * kpos;        // uniform SALU
        int kh = kpos / 3, kw = kpos - 3 * kh;
        int bko = ((kh - 1) * 56 + (kw - 1)) * 96 + cb * 32;
        gload16(&w1b[aw1 + t * 32], &lA[buf * 2048 + wave * 512]);
#pragma unroll
        for (int i = 0; i < 4; ++i) {
            const short* src = (((kh == 0) && top[i]) || ((kw == 0) && left[i]))
                             ? zbuf : &xt[xb0[i] + bko];
            gload16(src, &lB[buf * 8192 + i * 2048 + wave * 512]);
        }
    };

    f32x4 acc[4][4];
#pragma unroll
    for (int m = 0; m < 4; m++)
#pragma unroll
        for (int n = 0; n < 4; n++) acc[m][n] = (f32x4){0.f, 0.f, 0.f, 0.f};

    stage(0, 0);
    stage(1, 1);
    int cbuf = 0;
    for (int t = 0; t < 26; ++t) {        // K = 864 -> 27 steps
        WAITV(5);
        __builtin_amdgcn_s_barrier();
        if (t + 2 < 27) stage(nxt3(nxt3(cbuf)), t + 2);
        COMPUTE(acc, cbuf);
        cbuf = nxt3(cbuf);
    }
    WAITV(0);
    __builtin_amdgcn_s_barrier();
    COMPUTE(acc, cbuf);

    // epilogue: bias + rational -> act (NHWC, packed short4)
    float cnm[3][6], cdn[3][4];
#pragma unroll
    for (int i = 0; i < 6; i++) { cnm[0][i] = num_r[i]; cnm[1][i] = num_g[i]; cnm[2][i] = num_b[i]; }
#pragma unroll
    for (int i = 0; i < 4; i++) { cdn[0][i] = fabsf(den_r[i]); cdn[1][i] = fabsf(den_g[i]); cdn[2][i] = fabsf(den_b[i]); }

    int abase[4];
#pragma unroll
    for (int n = 0; n < 4; ++n) {
        int pp = p0 + wave * 64 + n * 16 + (lane & 15);
        int n2 = pp / 784; int r2 = pp - n2 * 784;
        int oh2 = r2 / 28; int ow2 = r2 - oh2 * 28;
        abase[n] = ((n2 * 30 + oh2 + 1) * 30 + ow2 + 1) * 192;
    }
#pragma unroll
    for (int m = 0; m < 4; ++m) {
        int cob = co0 + m * 16 + ((lane >> 4) << 2);
        float res[4][4];
#pragma unroll
        for (int r = 0; r < 4; ++r) {
            float nm[6], dn[4];
            sel_coeffs((cob + r) % 3, cnm, cdn, nm, dn);
            float bv = bias1[cob + r];
#pragma unroll
            for (int n = 0; n < 4; ++n)
                res[n][r] = rational_eval(acc[m][n][r] + bv, nm, dn);
        }
#pragma unroll
        for (int n = 0; n < 4; ++n) {
            bf16x4 pk;
#pragma unroll
            for (int r = 0; r < 4; ++r) pk[r] = f2bf(res[n][r]);
            *(bf16x4*)&act[abase[n] + cob] = pk;
        }
    }
}

// ---------------- kernel B: shortcut(1x1 s2, K=96) + conv2(3x3 s1, K=1728) into one acc;
//                  + fused bias + rational -> out (NCHW f32) ----------------
extern "C" __global__ __launch_bounds__(256)
void convB_kernel(const short* __restrict__ act,
                  const short* __restrict__ xt,
                  const short* __restrict__ w2b,
                  const short* __restrict__ wsb,
                  const float* __restrict__ bias2s,
                  const float* __restrict__ num_r, const float* __restrict__ den_r,
                  const float* __restrict__ num_g, const float* __restrict__ den_g,
                  const float* __restrict__ num_b, const float* __restrict__ den_b,
                  float* __restrict__ outp)
{
    __shared__ short lA[3 * 2048];
    __shared__ short lB[3 * 8192];

    const int tid  = threadIdx.x;
    const int lane = tid & 63;
    const int wave = tid >> 6;
    const int lbid = swz_bid(blockIdx.x);
    const int co0  = (lbid % 3) * 64;
    const int p0   = (lbid / 3) * 256;

    const int swz8 = ((tid & 3) ^ ((tid >> 3) & 3)) * 8;
    const int arow = tid >> 2;
    int ab[4], xc0[4];
#pragma unroll
    for (int i = 0; i < 4; ++i) {
        int p = p0 + arow + i * 64;
        int n = p / 784; int pr = p - n * 784;
        int oh = pr / 28; int ow = pr - oh * 28;
        ab[i]  = ((n * 30 + oh) * 30 + ow) * 192 + swz8;             // padded act
        xc0[i] = ((n * 56 + 2 * oh) * 56 + 2 * ow) * 96 + swz8;      // xt center tap
    }
    const int aw2 = (co0 + arow) * 1728 + swz8;
    const int awS = (co0 + arow) * 96 + swz8;

    const int ksl = lane >> 4;
    int ard[4], brd[4];
#pragma unroll
    for (int m = 0; m < 4; ++m) ard[m] = lidx(m * 16 + (lane & 15), ksl);
#pragma unroll
    for (int n = 0; n < 4; ++n) brd[n] = lidx(wave * 64 + n * 16 + (lane & 15), ksl);

    // t 0..2: shortcut GEMM steps; t 3..56: conv2 steps
    auto stage = [&](int buf, int t) {
        if (t < 3) {
            gload16(&wsb[awS + t * 32], &lA[buf * 2048 + wave * 512]);
#pragma unroll
            for (int i = 0; i < 4; ++i)
                gload16(&xt[xc0[i] + t * 32], &lB[buf * 8192 + i * 2048 + wave * 512]);
        } else {
            int u = t - 3;
            int kpos = u / 6, cb = u - 6 * kpos;
            int kh = kpos / 3, kw = kpos - 3 * kh;
            int bko = (kh * 30 + kw) * 192 + cb * 32;
            gload16(&w2b[aw2 + u * 32], &lA[buf * 2048 + wave * 512]);
#pragma unroll
            for (int i = 0; i < 4; ++i)
                gload16(&act[ab[i] + bko], &lB[buf * 8192 + i * 2048 + wave * 512]);
        }
    };

    f32x4 acc[4][4];
#pragma unroll
    for (int m = 0; m < 4; m++)
#pragma unroll
        for (int n = 0; n < 4; n++) acc[m][n] = (f32x4){0.f, 0.f, 0.f, 0.f};

    stage(0, 0);
    stage(1, 1);
    int cbuf = 0;
    for (int t = 0; t < 56; ++t) {        // 57 steps total
        WAITV(5);
        __builtin_amdgcn_s_barrier();
        if (t + 2 < 57) stage(nxt3(nxt3(cbuf)), t + 2);
        COMPUTE(acc, cbuf);
        cbuf = nxt3(cbuf);
    }
    WAITV(0);
    __builtin_amdgcn_s_barrier();
    COMPUTE(acc, cbuf);

    float cnm[3][6], cdn[3][4];
#pragma unroll
    for (int i = 0; i < 6; i++) { cnm[0][i] = num_r[i]; cnm[1][i] = num_g[i]; cnm[2][i] = num_b[i]; }
#pragma unroll
    for (int i = 0; i < 4; i++) { cdn[0][i] = fabsf(den_r[i]); cdn[1][i] = fabsf(den_g[i]); cdn[2][i] = fabsf(den_b[i]); }

    int obase[4];
#pragma unroll
    for (int n = 0; n < 4; ++n) {
        int pp = p0 + wave * 64 + n * 16 + (lane & 15);
        int n2 = pp / 784; int r2 = pp - n2 * 784;
        int oh2 = r2 / 28; int ow2 = r2 - oh2 * 28;
        obase[n] = n2 * (COUT * 784) + oh2 * 28 + ow2;
    }
#pragma unroll
    for (int m = 0; m < 4; ++m) {
        int cob = co0 + m * 16 + ((lane >> 4) << 2);
#pragma unroll
        for (int r = 0; r < 4; ++r) {
            float nm[6], dn[4];
            sel_coeffs((cob + r) % 3, cnm, cdn, nm, dn);
            float bv = bias2s[cob + r];
#pragma unroll
            for (int n = 0; n < 4; ++n) {
                int idx = obase[n] + (cob + r) * 784;
                outp[idx] = rational_eval(acc[m][n][r] + bv, nm, dn);
            }
        }
    }
}

// ---------------- launcher ----------------
extern "C" void kernel_launch(void* const* d_in, const int* in_sizes, int n_in,
                              void* d_out, int out_size, void* d_ws, size_t ws_size,
                              hipStream_t stream)
{
    const float* x      = (const float*)d_in[0];
    const float* w1     = (const float*)d_in[1];
    const float* gamma1 = (const float*)d_in[2];
    const float* beta1  = (const float*)d_in[3];
    const float* mean1  = (const float*)d_in[4];
    const float* var1   = (const float*)d_in[5];
    const float* num_r  = (const float*)d_in[6];
    const float* den_r  = (const float*)d_in[7];
    const float* num_g  = (const float*)d_in[8];
    const float* den_g  = (const float*)d_in[9];
    const float* num_b  = (const float*)d_in[10];
    const float* den_b  = (const float*)d_in[11];
    const float* w2     = (const float*)d_in[12];
    const float* gamma2 = (const float*)d_in[13];
    const float* beta2  = (const float*)d_in[14];
    const float* mean2  = (const float*)d_in[15];
    const float* var2   = (const float*)d_in[16];
    const float* wsc    = (const float*)d_in[17];
    const float* gammas = (const float*)d_in[18];
    const float* betas  = (const float*)d_in[19];
    const float* means  = (const float*)d_in[20];
    const float* vars_  = (const float*)d_in[21];

    char* base = (char*)d_ws;
    short* w1b  = (short*)(base + W1B_OFF);
    short* w2b  = (short*)(base + W2B_OFF);
    short* wsb  = (short*)(base + WSB_OFF);
    float* cs   = (float*)(base + CS_OFF);
    float* zb   = (float*)(base + ZB_OFF);
    short* xt   = (short*)(base + XT_OFF);
    short* act  = (short*)(base + ACT_OFF);
    float* outp = (float*)d_out;

    float* bias1  = cs + 576;
    float* bias2s = cs + 768;

    prep_scales_kernel<<<1, 256, 0, stream>>>(gamma1, beta1, mean1, var1,
                                              gamma2, beta2, mean2, var2,
                                              gammas, betas, means, vars_, cs, zb);

    prep_w_kernel<<<(COUT * CIN * 9 + 255) / 256, 256, 0, stream>>>(w1, cs, w1b, CIN, 9, COUT * CIN * 9);
    prep_w_kernel<<<(COUT * COUT * 9 + 255) / 256, 256, 0, stream>>>(w2, cs + 192, w2b, COUT, 9, COUT * COUT * 9);
    prep_w_kernel<<<(COUT * CIN + 255) / 256, 256, 0, stream>>>(wsc, cs + 384, wsb, CIN, 1, COUT * CIN);

    {
        int tot_a = 64 * (2 * 30 + 2 * 28) * 192;
        ring_zero_kernel<<<(tot_a + 255) / 256, 256, 0, stream>>>(act, 30, 192, tot_a);
    }

    xpose_kernel<<<64 * 56, 256, 0, stream>>>(x, xt);

    convA_kernel<<<GRID, 256, 0, stream>>>(xt, w1b, (const short*)zb, bias1,
                                           num_r, den_r, num_g, den_g, num_b, den_b,
                                           act);

    convB_kernel<<<GRID, 256, 0, stream>>>(act, xt, w2b, wsb, bias2s,
                                           num_r, den_r, num_g, den_g, num_b, den_b,
                                           outp);
}

// Round 9
// 143.843 us; speedup vs baseline: 1.9573x; 1.4527x over previous
//
#include <hip/hip_runtime.h>

#define EPSBN  1e-5f
#define NBLK   392           // 50176 px / 128 per block; 392 = 8*49

// ---------------- ws layout (bytes), total 61,701,888 <= 61,702,144 (proven fit) ----------------
#define W1B_OFF 0u           // bf16 [192][9][96]   -> 331776
#define W2B_OFF 331776u      // bf16 [192][9][192]  -> 663552
#define WSB_OFF 995328u      // bf16 [192][128]     -> 49152 (ch 96..127 zero; row0 pad doubles as zbuf)
#define CS_OFF  1044480u     // 960 f32 -> 3840
#define XT_OFF  1048320u     // bf16 [64][56][56][96] -> 38535168 (unpadded NHWC)
#define ACT_OFF 39583488u    // bf16 [64][30][30][192] -> 22118400 (padded NHWC)

typedef __attribute__((ext_vector_type(8))) short bf16x8;
typedef __attribute__((ext_vector_type(4))) short bf16x4;
typedef __attribute__((ext_vector_type(4))) float f32x4;

__device__ __forceinline__ short f2bf(float f) {
    unsigned u = __float_as_uint(f);
    u += 0x7fffu + ((u >> 16) & 1u);
    return (short)(u >> 16);
}

// direct global->LDS, 16B per lane; LDS dest = wave-uniform base + lane*16; global src per-lane
__device__ __forceinline__ void gload16(const short* g, short* l) {
    __builtin_amdgcn_global_load_lds(
        (const __attribute__((address_space(1))) void*)g,
        (__attribute__((address_space(3))) void*)l, 16, 0, 0);
}

__device__ __forceinline__ float rational_eval(float v, const float* nm, const float* dn) {
    float p = nm[5];
    p = p * v + nm[4];
    p = p * v + nm[3];
    p = p * v + nm[2];
    p = p * v + nm[1];
    p = p * v + nm[0];
    float xa = fabsf(v);
    float q = 1.0f;
    float pw = xa;
    q += dn[0] * pw; pw *= xa;
    q += dn[1] * pw; pw *= xa;
    q += dn[2] * pw; pw *= xa;
    q += dn[3] * pw;
    float inv = __builtin_amdgcn_rcpf(q);
    inv = inv * (2.0f - q * inv);
    return p * inv;
}

__device__ __forceinline__ void sel_coeffs(int v, const float cnm[3][6], const float cdn[3][4],
                                           float nm[6], float dn[4]) {
#pragma unroll
    for (int i = 0; i < 6; i++) nm[i] = (v == 0) ? cnm[0][i] : ((v == 1) ? cnm[1][i] : cnm[2][i]);
#pragma unroll
    for (int i = 0; i < 4; i++) dn[i] = (v == 0) ? cdn[0][i] : ((v == 1) ? cdn[1][i] : cdn[2][i]);
}

// ---------------- prep kernels ----------------
extern "C" __global__ void prep_scales_kernel(
    const float* g1, const float* b1, const float* m1, const float* v1,
    const float* g2, const float* b2, const float* m2, const float* v2,
    const float* gs, const float* bs, const float* ms, const float* vs,
    float* cs)
{
    int i = threadIdx.x;
    if (i < 192) {
        float a1 = g1[i] * rsqrtf(v1[i] + EPSBN);
        float a2 = g2[i] * rsqrtf(v2[i] + EPSBN);
        float a3 = gs[i] * rsqrtf(vs[i] + EPSBN);
        cs[i]       = a1;
        cs[192 + i] = a2;
        cs[384 + i] = a3;
        cs[576 + i] = b1[i] - m1[i] * a1;                          // bias1
        cs[768 + i] = (b2[i] - m2[i] * a2) + (bs[i] - ms[i] * a3); // bias2 + biass
    }
}

// w [co][ci][kpos] (OIHW) -> wb [co][kpos][ci_dst], scaled by s[co]; ci >= CI_src zero-padded
extern "C" __global__ void prep_w_kernel(const float* __restrict__ w, const float* __restrict__ s,
                                         short* __restrict__ wb, int CI_src, int CI_dst, int KP, int total)
{
    int i = blockIdx.x * 256 + threadIdx.x;
    if (i >= total) return;
    int co = i / (CI_dst * KP);
    int r  = i - co * CI_dst * KP;
    int kpos = r / CI_dst;
    int ci = r - kpos * CI_dst;
    wb[i] = (ci < CI_src) ? f2bf(w[(co * CI_src + ci) * KP + kpos] * s[co]) : (short)0;
}

// zero the border ring of a [64][H][H][C] bf16 buffer
extern "C" __global__ void ring_zero_kernel(short* __restrict__ buf, int H, int C, int total)
{
    int ring = 2 * H + 2 * (H - 2);
    int i = blockIdx.x * 256 + threadIdx.x;
    if (i >= total) return;
    int c = i % C;
    int t = i / C;
    int rp = t % ring;
    int n = t / ring;
    int h, w;
    if (rp < H)           { h = 0;          w = rp; }
    else if (rp < 2 * H)  { h = H - 1;      w = rp - H; }
    else { int k = rp - 2 * H; h = (k >> 1) + 1; w = (k & 1) ? (H - 1) : 0; }
    buf[((n * H + h) * H + w) * C + c] = 0;
}

// x NCHW f32 [64][96][56][56] -> xt NHWC bf16 [64][56][56][96]
extern "C" __global__ __launch_bounds__(256)
void xpose_kernel(const float* __restrict__ x, short* __restrict__ xt)
{
    __shared__ float t[96 * 57];
    int b = blockIdx.x;
    int n = b / 56, h = b - n * 56;
    const float* src = x + n * (96 * 3136) + h * 56;
    for (int i = threadIdx.x; i < 96 * 28; i += 256) {
        int c = i / 28, w2 = i - c * 28;
        float2 v = *(const float2*)&src[c * 3136 + w2 * 2];
        t[c * 57 + w2 * 2]     = v.x;
        t[c * 57 + w2 * 2 + 1] = v.y;
    }
    __syncthreads();
    unsigned* dst = (unsigned*)(xt + (n * 56 + h) * 56 * 96);
    for (int i = threadIdx.x; i < 56 * 48; i += 256) {
        int w = i / 96 * 0 + i / 48, cp = i - (i / 48) * 48;
        unsigned lo = (unsigned short)f2bf(t[(2 * cp) * 57 + w]);
        unsigned hi = (unsigned short)f2bf(t[(2 * cp + 1) * 57 + w]);
        dst[w * 48 + cp] = lo | (hi << 16);
    }
}

// ---------------- kernel A: conv1(3x3 s2)+BN1+rational -> act (NHWC bf16, padded) ----------------
// Block: 192co x 128px, 8 waves (4M x 2N), wave-tile 48x64, BK=32.
extern "C" __global__ __launch_bounds__(512, 4)
void convA_kernel(const short* __restrict__ xt,
                  const short* __restrict__ w1b,
                  const short* __restrict__ zbuf,
                  const float* __restrict__ bias1,
                  const float* __restrict__ num_r, const float* __restrict__ den_r,
                  const float* __restrict__ num_g, const float* __restrict__ den_g,
                  const float* __restrict__ num_b, const float* __restrict__ den_b,
                  short* __restrict__ act)
{
    __shared__ short lA[2][192 * 32];   // 12 KB each
    __shared__ short lB[2][128 * 32];   //  8 KB each  -> 40 KB total

    const int tid  = threadIdx.x;
    const int lane = tid & 63;
    const int wave = tid >> 6;
    const int wm = wave >> 1, wn = wave & 1;
    const int lbid = (blockIdx.x & 7) * 49 + (blockIdx.x >> 3);
    const int p0   = lbid * 128;

    // staging map: 4 lanes (16B slots) per row; source slot XOR-swizzled
    const int sA = (((tid & 3) ^ ((tid >> 3) & 3))) * 8;   // element offset within 32-k row
    const int r1 = tid >> 2;                                // 0..127
    const int aw1a = r1 * 864 + sA;
    const int aw1b = (128 + r1) * 864 + sA;                 // used by tid<256 only

    int xb0; bool top, left;
    {
        int p = p0 + r1;
        int n = p / 784; int pr = p - n * 784;
        int oh = pr / 28; int ow = pr - oh * 28;
        xb0 = ((n * 56 + 2 * oh) * 56 + 2 * ow) * 96 + sA;
        top = (oh == 0); left = (ow == 0);
    }

    // MFMA read offsets (swizzle-matched)
    const int l15 = lane & 15, ksl = lane >> 4;
    int ard[3], brd[4];
#pragma unroll
    for (int m = 0; m < 3; ++m) {
        int row = wm * 48 + m * 16 + l15;
        ard[m] = row * 32 + ((ksl ^ ((row >> 1) & 3)) << 3);
    }
#pragma unroll
    for (int n = 0; n < 4; ++n) {
        int row = wn * 64 + n * 16 + l15;
        brd[n] = row * 32 + ((ksl ^ ((row >> 1) & 3)) << 3);
    }

    auto stage = [&](int buf, int t) {
        int kpos = t / 3, cb = t - 3 * kpos;
        int kh = kpos / 3, kw = kpos - 3 * kh;
        gload16(&w1b[aw1a + t * 32], &lA[buf][wave * 512]);
        if (tid < 256) gload16(&w1b[aw1b + t * 32], &lA[buf][4096 + wave * 512]);
        int bko = ((kh - 1) * 56 + (kw - 1)) * 96 + cb * 32;
        const short* src = (((kh == 0) && top) || ((kw == 0) && left)) ? zbuf : &xt[xb0 + bko];
        gload16(src, &lB[buf][wave * 512]);
    };

    f32x4 acc[3][4];
#pragma unroll
    for (int m = 0; m < 3; m++)
#pragma unroll
        for (int n = 0; n < 4; n++) acc[m][n] = (f32x4){0.f, 0.f, 0.f, 0.f};

    stage(0, 0);
    int cur = 0;
    for (int t = 0; t < 27; ++t) {
        __syncthreads();                      // drains vmcnt -> buf[cur] ready for all waves
        if (t + 1 < 27) stage(cur ^ 1, t + 1);
        bf16x8 af[3];
#pragma unroll
        for (int m = 0; m < 3; ++m) af[m] = *(const bf16x8*)&lA[cur][ard[m]];
#pragma unroll
        for (int n = 0; n < 4; ++n) {
            bf16x8 bv = *(const bf16x8*)&lB[cur][brd[n]];
#pragma unroll
            for (int m = 0; m < 3; ++m)
                acc[m][n] = __builtin_amdgcn_mfma_f32_16x16x32_bf16(af[m], bv, acc[m][n], 0, 0, 0);
        }
        cur ^= 1;
    }

    // epilogue: bias + rational -> act (NHWC, packed short4)
    float cnm[3][6], cdn[3][4];
#pragma unroll
    for (int i = 0; i < 6; i++) { cnm[0][i] = num_r[i]; cnm[1][i] = num_g[i]; cnm[2][i] = num_b[i]; }
#pragma unroll
    for (int i = 0; i < 4; i++) { cdn[0][i] = fabsf(den_r[i]); cdn[1][i] = fabsf(den_g[i]); cdn[2][i] = fabsf(den_b[i]); }

    int abase[4];
#pragma unroll
    for (int n = 0; n < 4; ++n) {
        int pp = p0 + wn * 64 + n * 16 + l15;
        int n2 = pp / 784; int r2 = pp - n2 * 784;
        int oh2 = r2 / 28; int ow2 = r2 - oh2 * 28;
        abase[n] = ((n2 * 30 + oh2 + 1) * 30 + ow2 + 1) * 192;
    }
#pragma unroll
    for (int m = 0; m < 3; ++m) {
        int cob = wm * 48 + m * 16 + (ksl << 2);
        float res[4][4];
#pragma unroll
        for (int r = 0; r < 4; ++r) {
            float nm[6], dn[4];
            sel_coeffs((cob + r) % 3, cnm, cdn, nm, dn);
            float bv = bias1[cob + r];
#pragma unroll
            for (int n = 0; n < 4; ++n)
                res[n][r] = rational_eval(acc[m][n][r] + bv, nm, dn);
        }
#pragma unroll
        for (int n = 0; n < 4; ++n) {
            bf16x4 pk;
#pragma unroll
            for (int r = 0; r < 4; ++r) pk[r] = f2bf(res[n][r]);
            *(bf16x4*)&act[abase[n] + cob] = pk;
        }
    }
}

// ---------------- kernel B: shortcut(1x1 s2, padded K=128) + conv2(3x3 s1, K=1728) into one acc;
//                  + fused bias + rational -> out (NCHW f32). Block 192co x 128px, BK=64. ----------------
extern "C" __global__ __launch_bounds__(512, 4)
void convB_kernel(const short* __restrict__ act,
                  const short* __restrict__ xt,
                  const short* __restrict__ w2b,
                  const short* __restrict__ wsb,
                  const float* __restrict__ bias2s,
                  const float* __restrict__ num_r, const float* __restrict__ den_r,
                  const float* __restrict__ num_g, const float* __restrict__ den_g,
                  const float* __restrict__ num_b, const float* __restrict__ den_b,
                  float* __restrict__ outp)
{
    __shared__ short lA[2][192 * 64];   // 24 KB each
    __shared__ short lB[2][128 * 64];   // 16 KB each -> 80 KB total

    const int tid  = threadIdx.x;
    const int lane = tid & 63;
    const int wave = tid >> 6;
    const int wm = wave >> 1, wn = wave & 1;
    const int lbid = (blockIdx.x & 7) * 49 + (blockIdx.x >> 3);
    const int p0   = lbid * 128;

    // staging map: 8 lanes (16B slots) per 64-k row; source slot XOR-swizzled by row&7
    const int s8 = (((tid & 7) ^ ((tid >> 3) & 7))) * 8;
    const int rA = tid >> 3;    // 0..63

    int awW[3], awS[3];
#pragma unroll
    for (int c = 0; c < 3; ++c) {
        int row = c * 64 + rA;
        awW[c] = row * 1728 + s8;
        awS[c] = row * 128 + s8;
    }
    int abB[2], xcB[2];
#pragma unroll
    for (int c = 0; c < 2; ++c) {
        int p = p0 + c * 64 + rA;
        int n = p / 784; int pr = p - n * 784;
        int oh = pr / 28; int ow = pr - oh * 28;
        abB[c] = ((n * 30 + oh) * 30 + ow) * 192 + s8;
        xcB[c] = ((n * 56 + 2 * oh) * 56 + 2 * ow) * 96 + s8;
    }

    const int l15 = lane & 15, ksl = lane >> 4;
    int ard[2][3], brd[2][4];
#pragma unroll
    for (int kk = 0; kk < 2; ++kk) {
#pragma unroll
        for (int m = 0; m < 3; ++m) {
            int row = wm * 48 + m * 16 + l15;
            ard[kk][m] = row * 64 + ((((kk << 2) | ksl) ^ (row & 7)) << 3);
        }
#pragma unroll
        for (int n = 0; n < 4; ++n) {
            int row = wn * 64 + n * 16 + l15;
            brd[kk][n] = row * 64 + ((((kk << 2) | ksl) ^ (row & 7)) << 3);
        }
    }

    // t 0..1: shortcut (wsb padded to 128 ch); t 2..28: conv2 (9 taps x 3 cb64)
    auto stage = [&](int buf, int t) {
        if (t < 2) {
#pragma unroll
            for (int c = 0; c < 3; ++c)
                gload16(&wsb[awS[c] + t * 64], &lA[buf][c * 4096 + wave * 512]);
#pragma unroll
            for (int c = 0; c < 2; ++c)
                gload16(&xt[xcB[c] + t * 64], &lB[buf][c * 4096 + wave * 512]);
        } else {
            int u = t - 2;
            int kpos = u / 3, cb = u - 3 * kpos;
            int kh = kpos / 3, kw = kpos - 3 * kh;
            int bko = (kh * 30 + kw) * 192 + cb * 64;
#pragma unroll
            for (int c = 0; c < 3; ++c)
                gload16(&w2b[awW[c] + u * 64], &lA[buf][c * 4096 + wave * 512]);
#pragma unroll
            for (int c = 0; c < 2; ++c)
                gload16(&act[abB[c] + bko], &lB[buf][c * 4096 + wave * 512]);
        }
    };

    f32x4 acc[3][4];
#pragma unroll
    for (int m = 0; m < 3; m++)
#pragma unroll
        for (int n = 0; n < 4; n++) acc[m][n] = (f32x4){0.f, 0.f, 0.f, 0.f};

    stage(0, 0);
    int cur = 0;
    for (int t = 0; t < 29; ++t) {
        __syncthreads();
        if (t + 1 < 29) stage(cur ^ 1, t + 1);
#pragma unroll
        for (int kk = 0; kk < 2; ++kk) {
            bf16x8 af[3];
#pragma unroll
            for (int m = 0; m < 3; ++m) af[m] = *(const bf16x8*)&lA[cur][ard[kk][m]];
#pragma unroll
            for (int n = 0; n < 4; ++n) {
                bf16x8 bv = *(const bf16x8*)&lB[cur][brd[kk][n]];
#pragma unroll
                for (int m = 0; m < 3; ++m)
                    acc[m][n] = __builtin_amdgcn_mfma_f32_16x16x32_bf16(af[m], bv, acc[m][n], 0, 0, 0);
            }
        }
        cur ^= 1;
    }

    float cnm[3][6], cdn[3][4];
#pragma unroll
    for (int i = 0; i < 6; i++) { cnm[0][i] = num_r[i]; cnm[1][i] = num_g[i]; cnm[2][i] = num_b[i]; }
#pragma unroll
    for (int i = 0; i < 4; i++) { cdn[0][i] = fabsf(den_r[i]); cdn[1][i] = fabsf(den_g[i]); cdn[2][i] = fabsf(den_b[i]); }

    int obase[4];
#pragma unroll
    for (int n = 0; n < 4; ++n) {
        int pp = p0 + wn * 64 + n * 16 + l15;
        int n2 = pp / 784; int r2 = pp - n2 * 784;
        int oh2 = r2 / 28; int ow2 = r2 - oh2 * 28;
        obase[n] = n2 * (192 * 784) + oh2 * 28 + ow2;
    }
#pragma unroll
    for (int m = 0; m < 3; ++m) {
        int cob = wm * 48 + m * 16 + (ksl << 2);
#pragma unroll
        for (int r = 0; r < 4; ++r) {
            float nm[6], dn[4];
            sel_coeffs((cob + r) % 3, cnm, cdn, nm, dn);
            float bv = bias2s[cob + r];
#pragma unroll
            for (int n = 0; n < 4; ++n) {
                int idx = obase[n] + (cob + r) * 784;
                outp[idx] = rational_eval(acc[m][n][r] + bv, nm, dn);
            }
        }
    }
}

// ---------------- launcher ----------------
extern "C" void kernel_launch(void* const* d_in, const int* in_sizes, int n_in,
                              void* d_out, int out_size, void* d_ws, size_t ws_size,
                              hipStream_t stream)
{
    const float* x      = (const float*)d_in[0];
    const float* w1     = (const float*)d_in[1];
    const float* gamma1 = (const float*)d_in[2];
    const float* beta1  = (const float*)d_in[3];
    const float* mean1  = (const float*)d_in[4];
    const float* var1   = (const float*)d_in[5];
    const float* num_r  = (const float*)d_in[6];
    const float* den_r  = (const float*)d_in[7];
    const float* num_g  = (const float*)d_in[8];
    const float* den_g  = (const float*)d_in[9];
    const float* num_b  = (const float*)d_in[10];
    const float* den_b  = (const float*)d_in[11];
    const float* w2     = (const float*)d_in[12];
    const float* gamma2 = (const float*)d_in[13];
    const float* beta2  = (const float*)d_in[14];
    const float* mean2  = (const float*)d_in[15];
    const float* var2   = (const float*)d_in[16];
    const float* wsc    = (const float*)d_in[17];
    const float* gammas = (const float*)d_in[18];
    const float* betas  = (const float*)d_in[19];
    const float* means  = (const float*)d_in[20];
    const float* vars_  = (const float*)d_in[21];

    char* base = (char*)d_ws;
    short* w1b  = (short*)(base + W1B_OFF);
    short* w2b  = (short*)(base + W2B_OFF);
    short* wsb  = (short*)(base + WSB_OFF);
    float* cs   = (float*)(base + CS_OFF);
    short* xt   = (short*)(base + XT_OFF);
    short* act  = (short*)(base + ACT_OFF);
    float* outp = (float*)d_out;

    float* bias1  = cs + 576;
    float* bias2s = cs + 768;
    const short* zbuf = wsb + 96;   // row 0's zero-padded channels (64 B of zeros)

    prep_scales_kernel<<<1, 256, 0, stream>>>(gamma1, beta1, mean1, var1,
                                              gamma2, beta2, mean2, var2,
                                              gammas, betas, means, vars_, cs);

    prep_w_kernel<<<(192 * 96 * 9 + 255) / 256, 256, 0, stream>>>(w1, cs, w1b, 96, 96, 9, 192 * 96 * 9);
    prep_w_kernel<<<(192 * 192 * 9 + 255) / 256, 256, 0, stream>>>(w2, cs + 192, w2b, 192, 192, 9, 192 * 192 * 9);
    prep_w_kernel<<<(192 * 128 + 255) / 256, 256, 0, stream>>>(wsc, cs + 384, wsb, 96, 128, 1, 192 * 128);

    {
        int tot_a = 64 * (2 * 30 + 2 * 28) * 192;
        ring_zero_kernel<<<(tot_a + 255) / 256, 256, 0, stream>>>(act, 30, 192, tot_a);
    }

    xpose_kernel<<<64 * 56, 256, 0, stream>>>(x, xt);

    convA_kernel<<<NBLK, 512, 0, stream>>>(xt, w1b, zbuf, bias1,
                                           num_r, den_r, num_g, den_g, num_b, den_b,
                                           act);

    convB_kernel<<<NBLK, 512, 0, stream>>>(act, xt, w2b, wsb, bias2s,
                                           num_r, den_r, num_g, den_g, num_b, den_b,
                                           outp);
}